// Round 16
// baseline (160.906 us; speedup 1.0000x reference)
//
#include <hip/hip_runtime.h>

typedef float v4f __attribute__((ext_vector_type(4)));
typedef unsigned int u32;
typedef unsigned short u16;

#define STR 76   // LDS row stride in bf16 units (152B: step 38 words ≡ 6 mod 32 -> 2-way max, free)

__device__ __forceinline__ float b2f(u16 u) {
    union { float f; u32 i; } c; c.i = ((u32)u) << 16; return c.f;
}
__device__ __forceinline__ u16 f2b(float f) {
    union { float f; u32 i; } c; c.f = f;
    u32 r = c.i + 0x7fffu + ((c.i >> 16) & 1u);   // RNE
    return (u16)(r >> 16);
}

// Block = (n, half of T) = 8 segments. Grid 256 = 1 block/CU, 8 waves.
// Double-buffered bf16 segment tiles. Per slot: B(i) all-waves gate math; then
// waves 4-7 stage seg i+1 (HBM READ stream) || waves 0-3 apply seg i (HBM WRITE
// stream) -> both streams concurrently active on every CU (mixed-copy regime).
__global__ __launch_bounds__(512, 2) void k_ws(
    const float* __restrict__ x,
    const float* __restrict__ wsq, const float* __restrict__ bsq,
    const float* __restrict__ gamma, const float* __restrict__ beta,
    const float* __restrict__ rmean, const float* __restrict__ rvar,
    const float* __restrict__ wc1, const float* __restrict__ bc1,
    const float* __restrict__ wex, const float* __restrict__ bex,
    float* __restrict__ out)
{
    __shared__ u16   buf[2][256 * STR];   // 2 x 38,912 B
    __shared__ float xb[768];             // means-sums [t][c]
    __shared__ float gs[768];             // gate [c][t]
    __shared__ float part[384];           // squeeze partials [t][r][g]
    __shared__ float ybn[48], y1[48], mv[48];

    const int tid  = threadIdx.x;
    const int wv   = tid >> 6;
    const int atid = tid & 255;           // lane id within each 4-wave group
    const unsigned bid = blockIdx.x;
    const unsigned o    = (bid & 7u) * 32u + (bid >> 3);   // bijective XCD chunk swizzle (256=8*32)
    const unsigned n    = o >> 1;
    const unsigned half = o & 1u;

    const float* xn = x   + (size_t)n * 307200u + half * 600u;   // + c*1200 + i*75 + m
    float*       on = out + (size_t)n * 307200u + half * 600u;

    // ---- A: stage segment i -> buf[i&1] (R6-proven coalesced addressing) ----
    auto stageA = [&](int i, int h) {
        u16* B = buf[i & 1];
        const float* sb = xn + i * 75;
        #pragma unroll
        for (int it = 0; it < 18; ++it) {             // interior: 18 f4/channel
            int j = it * 256 + atid;
            int c = j / 18, k = j - c * 18;
            v4f v = *(const v4f*)(sb + c * 1200 + h + 4 * k);
            u32 p0 = (u32)f2b(v.x) | ((u32)f2b(v.y) << 16);
            u32 p1 = (u32)f2b(v.z) | ((u32)f2b(v.w) << 16);
            u32 s = (u32)(c * STR + 4 * k);
            *(u32*)&B[s]     = p0;
            *(u32*)&B[s + 2] = p1;
        }
        #pragma unroll
        for (int it = 0; it < 3; ++it) {              // 3 edge scalars/channel
            int j = it * 256 + atid;
            int c = j / 3, e = j - c * 3;
            int m = (e < h) ? e : e + 72;
            B[c * STR + 72 + e] = f2b(sb[c * 1200 + m]);
        }
    };

    // ---- D: apply gate to segment i from buf[i&1], NT store ----
    auto applyD = [&](int i, int h) {
        const u16* B = buf[i & 1];
        float* ob = on + i * 75;
        #pragma unroll
        for (int it = 0; it < 18; ++it) {
            int j = it * 256 + atid;
            int c = j / 18, k = j - c * 18;
            u32 s  = (u32)(c * STR + 4 * k);
            u32 q0 = *(const u32*)&B[s];
            u32 q1 = *(const u32*)&B[s + 2];
            int m0  = h + 4 * k;
            int t0  = (m0 * 41) >> 10;                 // m0/25 (exact, m0<1024)
            int t3  = ((m0 + 3) * 41) >> 10;
            int rem = m0 - t0 * 25;
            float g0 = gs[c * 3 + t0];
            float g3 = gs[c * 3 + t3];
            v4f ov;
            ov.x = b2f((u16)(q0 & 0xffffu)) * g0;
            ov.y = b2f((u16)(q0 >> 16))     * ((rem + 1 < 25) ? g0 : g3);
            ov.z = b2f((u16)(q1 & 0xffffu)) * ((rem + 2 < 25) ? g0 : g3);
            ov.w = b2f((u16)(q1 >> 16))     * ((rem + 3 < 25) ? g0 : g3);
            __builtin_nontemporal_store(ov, (v4f*)(ob + c * 1200 + h + 4 * k));
        }
        #pragma unroll
        for (int it = 0; it < 3; ++it) {
            int j = it * 256 + atid;
            int c = j / 3, e = j - c * 3;
            int m = (e < h) ? e : e + 72;
            int t = (e < h) ? 0 : 2;
            float val = b2f(B[c * STR + 72 + e]) * gs[c * 3 + t];
            __builtin_nontemporal_store(val, ob + c * 1200 + m);
        }
    };

    // ---- B: means reduce + gate chain for segment i (all waves, barriered) ----
    auto bPhase = [&](int i, int h) {
        const u16* B = buf[i & 1];
        for (int p = tid; p < 768; p += 512) {        // 768 frame sums (c,t)
            int c = p & 255, t = p >> 8;
            float s = 0.f;
            #pragma unroll
            for (int v = 0; v < 25; ++v) {
                int m  = t * 25 + v;
                int sl = (m >= h && m < h + 72) ? (m - h) : ((m < h) ? 72 + m : m);
                s += b2f(B[c * STR + sl]);
            }
            xb[t * 256 + c] = s;
        }
        __syncthreads();
        if (tid < 384) {                              // B1: squeeze partials (t,r,g)
            int g = tid & 7, q = tid >> 3, t = q >> 4, r = q & 15;
            float acc = 0.f;
            #pragma unroll 8
            for (int ii = 0; ii < 32; ++ii) {
                int c = g * 32 + ii;
                acc += xb[t * 256 + c] * wsq[r * 256 + c];
            }
            part[tid] = acc;                          // [(t*16+r)*8+g]: lane-linear
        }
        __syncthreads();
        if (tid < 48) {                               // combine + BN (bsq, 1/25 folded)
            int t = tid >> 4, r = tid & 15;
            float acc = 0.f;
            #pragma unroll
            for (int g = 0; g < 8; ++g) acc += part[((t * 16 + r) << 3) + g];
            float sc = gamma[r] * rsqrtf(rvar[r] + 1e-5f);
            ybn[tid] = acc * (0.04f * sc) + (bsq[r] * sc + beta[r] - rmean[r] * sc);
        }
        __syncthreads();
        if (tid < 48) {                               // conv1
            int t = tid >> 4, s = tid & 15;
            float acc = bc1[s];
            #pragma unroll
            for (int r = 0; r < 16; ++r) acc += ybn[t * 16 + r] * wc1[s * 16 + r];
            y1[tid] = acc;
        }
        __syncthreads();
        if (tid < 48) {                               // temporal diff
            int t = tid >> 4;
            mv[tid] = (t < 2) ? (y1[tid + 16] - ybn[tid]) : 0.f;
        }
        __syncthreads();
        if (tid < 256) {                              // expand + sigmoid (c)
            int c = tid;
            float be = bex[c];
            float a0 = be, a1 = be, a2 = be;
            #pragma unroll
            for (int r = 0; r < 16; ++r) {
                float w = wex[c * 16 + r];
                a0 += mv[r] * w; a1 += mv[16 + r] * w; a2 += mv[32 + r] * w;
            }
            gs[c * 3 + 0] = 1.f / (1.f + expf(-a0));
            gs[c * 3 + 1] = 1.f / (1.f + expf(-a1));
            gs[c * 3 + 2] = 1.f / (1.f + expf(-a2));
        }
        __syncthreads();
    };

    // ---- prologue: stage segment 0 ----
    if (wv >= 4) stageA(0, 0);
    __syncthreads();

    // ---- 8-slot pipeline: B(i); then A(i+1) || D(i) ----
    #pragma unroll
    for (int i = 0; i < 8; ++i) {
        const int h = i & 3;                          // (i*75) alignment shift
        bPhase(i, h);
        if (wv >= 4) {
            if (i < 7) stageA(i + 1, (i + 1) & 3);    // HBM read stream
        } else {
            applyD(i, h);                             // HBM write stream
        }
        __syncthreads();
    }
}

extern "C" void kernel_launch(void* const* d_in, const int* in_sizes, int n_in,
                              void* d_out, int out_size, void* d_ws, size_t ws_size,
                              hipStream_t stream) {
    const float* x     = (const float*)d_in[0];
    const float* wsq   = (const float*)d_in[1];
    const float* bsq   = (const float*)d_in[2];
    const float* gamma = (const float*)d_in[3];
    const float* beta  = (const float*)d_in[4];
    const float* rmean = (const float*)d_in[5];
    const float* rvar  = (const float*)d_in[6];
    const float* wc1   = (const float*)d_in[7];
    const float* bc1   = (const float*)d_in[8];
    const float* wex   = (const float*)d_in[9];
    const float* bex   = (const float*)d_in[10];

    k_ws<<<256, 512, 0, stream>>>(x, wsq, bsq, gamma, beta,
                                  rmean, rvar, wc1, bc1, wex, bex,
                                  (float*)d_out);
}

// Round 17
// 77.015 us; speedup vs baseline: 2.0893x; 2.0893x over previous
//
#include <hip/hip_runtime.h>

typedef float v4f __attribute__((ext_vector_type(4)));

// R11 structure (best measured: 85.6us), conflict-fixed + idle-wave B1:
//   Block = (n, quad of 4 segments), grid 512, 512 threads, 2 blocks/CU.
//   16 chunks of 16 channels, double-buffered f32 staging (stride-77 f4):
//     waves 6,7: stage chunk i+1 (HBM read)   [R11-proven coalesced]
//     waves 0-2: frame-sum reduce chunk i -> xb[t][c] (t-major: clean banks)
//     waves 3-5: B1 squeeze-accumulate chunk i-1 into REGISTERS
//                (xb reads broadcast across r-lanes, wsqL stride-1: conflict-free)
//   Epilogue: BN (acc already done) -> conv1 -> diff -> expand -> apply.
//   Apply re-reads x from L3 (R10/R11/R13-proven) + NT stores. gs aliases buf.
__global__ __launch_bounds__(512, 4) void k_fused8(
    const float* __restrict__ x,
    const float* __restrict__ wsq, const float* __restrict__ bsq,
    const float* __restrict__ gamma, const float* __restrict__ beta,
    const float* __restrict__ rmean, const float* __restrict__ rvar,
    const float* __restrict__ wc1, const float* __restrict__ bc1,
    const float* __restrict__ wex, const float* __restrict__ bex,
    float* __restrict__ out)
{
    __shared__ v4f   buf[2][16 * 77];   // 2 x 19,712 B staging (pad 77: ~2-way reads)
    __shared__ float xb[12 * 256];      // frame sums [t][c]  (t-major!)   12,288 B
    __shared__ float wsqL[256 * 17];    // wsq transposed [c][r]           17,408 B
    __shared__ float ybn[192], y1[192], mv[192];

    const int tid = threadIdx.x;
    const unsigned bid = blockIdx.x;
    const unsigned o = (bid & 7u) * 64u + (bid >> 3);   // bijective XCD chunk swizzle
    const unsigned n = o >> 2;
    const unsigned q = o & 3u;

    const v4f* x4 = (const v4f*)x + (size_t)n * 76800u + q * 75u;   // + c*300 + k
    v4f*       o4 = (v4f*)out     + (size_t)n * 76800u + q * 75u;

    float* gsb = (float*)buf;           // gate [c*12+t], aliases buf after loop

    float acc = 0.f;                    // B1 accumulator (lanes 192..383)

    // producers (tid>=384): stage chunk cg (16 ch x 75 f4), reg-batched
    auto stage = [&](int cg, v4f* dst) {
        const int pt = tid - 384;       // 0..127
        v4f tmp[10];
        #pragma unroll
        for (int i = 0; i < 10; ++i) {
            int s = i * 128 + pt;
            int sc = (s < 1200) ? s : 1199;
            int c = sc / 75, k = sc - c * 75;
            tmp[i] = x4[(cg * 16 + c) * 300 + k];
        }
        #pragma unroll
        for (int i = 0; i < 10; ++i) {
            int s = i * 128 + pt;
            int sc = (s < 1200) ? s : 1199;
            int c = sc / 75, k = sc - c * 75;
            dst[c * 77 + k] = tmp[i];   // dup writes for pad lanes: same data, benign
        }
    };
    // consumers (tid<192): frame sums of chunk cg from staged buffer
    auto reduceC = [&](int cg) {
        int t = tid >> 4, cl = tid & 15;
        const float* bp = (const float*)&buf[cg & 1][cl * 77] + t * 25;
        float s = 0.f;
        #pragma unroll
        for (int v = 0; v < 25; ++v) s += bp[v];
        xb[t * 256 + cg * 16 + cl] = s;              // [t][c]: 4-way write max (tiny)
    };
    // B1 accumulators (192<=tid<384): += chunk cg's 16 channels
    auto accumB1 = [&](int cg) {
        int u = tid - 192, t = u >> 4, r = u & 15;
        #pragma unroll
        for (int i = 0; i < 16; ++i) {
            int c = cg * 16 + i;
            acc += xb[t * 256 + c] * wsqL[c * 17 + r];   // xb broadcast, wsqL spread
        }
    };

    // ---- prologue: wsq -> LDS transposed; stage chunk 0 ----
    #pragma unroll
    for (int it = 0; it < 8; ++it) {
        int j = it * 512 + tid;                      // j = r*256 + c
        wsqL[(j & 255) * 17 + (j >> 8)] = wsq[j];
    }
    if (tid >= 384) stage(0, buf[0]);
    __syncthreads();

    // ---- 16-chunk pipeline: stage(i+1) || reduce(i) || accum(i-1) ----
    for (int i = 0; i < 16; ++i) {
        if (tid >= 384) { if (i < 15) stage(i + 1, buf[(i + 1) & 1]); }
        else if (tid < 192) reduceC(i);
        else if (i > 0) accumB1(i - 1);
        __syncthreads();
    }

    // ---- epilogue: finish B1 + BN (accum lanes), conv1, diff, expand ----
    if (tid >= 192 && tid < 384) {
        accumB1(15);
        int u = tid - 192, r = u & 15;
        float sc = gamma[r] * rsqrtf(rvar[r] + 1e-5f);
        ybn[u] = acc * (0.04f * sc) + (bsq[r] * sc + beta[r] - rmean[r] * sc);
    }
    __syncthreads();
    if (tid < 192) {                                 // conv1
        int t = tid >> 4, s = tid & 15;
        float a = bc1[s];
        #pragma unroll
        for (int r = 0; r < 16; ++r) a += ybn[t * 16 + r] * wc1[s * 16 + r];
        y1[tid] = a;
    }
    __syncthreads();
    if (tid < 192) {                                 // temporal diff (4 whole segs)
        int t = tid >> 4;
        mv[tid] = ((t % 3) < 2) ? (y1[tid + 16] - ybn[tid]) : 0.f;
    }
    __syncthreads();
    {                                                // expand + sigmoid (c, t-half)
        int c = tid & 255, half = tid >> 8;
        float wexr[16];
        #pragma unroll
        for (int r = 0; r < 16; ++r) wexr[r] = wex[c * 16 + r];
        float be = bex[c];
        #pragma unroll
        for (int t = half * 6; t < half * 6 + 6; ++t) {
            float a = be;
            #pragma unroll
            for (int r = 0; r < 16; ++r) a += mv[t * 16 + r] * wexr[r];
            gsb[c * 12 + t] = 1.f / (1.f + expf(-a));
        }
    }
    __syncthreads();

    // ---- apply: re-read x (L3-hot), gate, NT float4 store (R11 verbatim) ----
    #pragma unroll 4
    for (int it = 0; it < 38; ++it) {
        int j = it * 512 + tid;
        if (j < 19200) {
            unsigned c = ((unsigned)j * 55926u) >> 22;   // j/75 (exact j<19200)
            int k = j - (int)c * 75;
            v4f v = x4[c * 300 + k];
            int m0  = k * 4;
            int t0  = (m0 * 41) >> 10;                   // m0/25 (exact m0<1024)
            int t3  = ((m0 + 3) * 41) >> 10;
            int rem = m0 - t0 * 25;
            float g0 = gsb[c * 12 + t0];
            float g3 = gsb[c * 12 + t3];
            v4f ov;
            ov.x = v.x * g0;
            ov.y = v.y * ((rem + 1 < 25) ? g0 : g3);
            ov.z = v.z * ((rem + 2 < 25) ? g0 : g3);
            ov.w = v.w * ((rem + 3 < 25) ? g0 : g3);
            __builtin_nontemporal_store(ov, &o4[c * 300 + k]);
        }
    }
}

extern "C" void kernel_launch(void* const* d_in, const int* in_sizes, int n_in,
                              void* d_out, int out_size, void* d_ws, size_t ws_size,
                              hipStream_t stream) {
    const float* x     = (const float*)d_in[0];
    const float* wsq   = (const float*)d_in[1];
    const float* bsq   = (const float*)d_in[2];
    const float* gamma = (const float*)d_in[3];
    const float* beta  = (const float*)d_in[4];
    const float* rmean = (const float*)d_in[5];
    const float* rvar  = (const float*)d_in[6];
    const float* wc1   = (const float*)d_in[7];
    const float* bc1   = (const float*)d_in[8];
    const float* wex   = (const float*)d_in[9];
    const float* bex   = (const float*)d_in[10];

    k_fused8<<<512, 512, 0, stream>>>(x, wsq, bsq, gamma, beta,
                                      rmean, rvar, wc1, bc1, wex, bex,
                                      (float*)d_out);
}